// Round 1
// 212.118 us; speedup vs baseline: 1.0630x; 1.0630x over previous
//
#include <hip/hip_runtime.h>
#include <hip/hip_fp16.h>

#define D_ 160
#define H_ 192
#define W_ 160
constexpr int NV = D_ * H_ * W_;   // 4,915,200 (even)

typedef float        f32x4 __attribute__((ext_vector_type(4)));
typedef unsigned int u32x4 __attribute__((ext_vector_type(4)));

// ---------------------------------------------------------------------------
// Pass 1: convert vol f32[NV][4] -> packed half4 (uint2) in d_ws.
// 2 voxels/thread: 32 B read (non-temporal; read-once), 16 B write, coalesced.
// ---------------------------------------------------------------------------
__global__ __launch_bounds__(256) void vol_to_half_kernel(
    const float4* __restrict__ vol, uint4* __restrict__ volh2)
{
    int i = blockIdx.x * 256 + threadIdx.x;   // pair index
    if (i >= NV / 2) return;
    f32x4 a = __builtin_nontemporal_load((const f32x4*)(vol + 2 * i));
    f32x4 b = __builtin_nontemporal_load((const f32x4*)(vol + 2 * i + 1));
    __half2 a01 = __floats2half2_rn(a.x, a.y);
    __half2 a23 = __floats2half2_rn(a.z, a.w);
    __half2 b01 = __floats2half2_rn(b.x, b.y);
    __half2 b23 = __floats2half2_rn(b.z, b.w);
    uint4 p;
    p.x = *(unsigned int*)&a01;
    p.y = *(unsigned int*)&a23;
    p.z = *(unsigned int*)&b01;
    p.w = *(unsigned int*)&b23;
    volh2[i] = p;
}

__device__ inline float4 h4_to_f4(uint2 p) {
    __half2 ab = *(__half2*)&p.x;
    __half2 cd = *(__half2*)&p.y;
    float2 f0 = __half22float2(ab);
    float2 f1 = __half22float2(cd);
    return make_float4(f0.x, f0.y, f1.x, f1.y);
}

// Load the (x0, x1) corner pair of one row with ONE 16-B load at the 8-B
// aligned address &row[a], a = min(ix0, W-2). For interior ix0 the halves are
// (v[ix0], v[ix0+1]); at the clamp edge (ix0 == W-1) we need (v[W-1], v[W-1]),
// i.e. (hi, hi). Note v_x1 is ALWAYS the high half.
__device__ inline void load_pair(const uint2* __restrict__ p, bool edge,
                                 float4& v0, float4& v1)
{
    u32x4 q;
    __builtin_memcpy(&q, p, 16);      // align-8 16B load (gfx950 unaligned-ok)
    uint2 lo, hi;
    lo.x = q[0]; lo.y = q[1];
    hi.x = q[2]; hi.y = q[3];
    float4 fl = h4_to_f4(lo);
    float4 fh = h4_to_f4(hi);
    v1 = fh;
    v0 = edge ? fh : fl;
}

// ---------------------------------------------------------------------------
// Pass 2: trilinear gather from half-packed volume.
// 4 paired 16-B gathers instead of 8 8-B gathers (half the TA line-visits);
// df loads and out stores are non-temporal so L2 stays reserved for vol.
// ---------------------------------------------------------------------------
__global__ __launch_bounds__(256) void st_half_kernel(
    const uint2* __restrict__ volh,   // [D,H,W] of half4 (8 B)
    const float* __restrict__ df,     // [D,H,W,3]
    float*       __restrict__ out)    // [D,H,W,4] f32
{
    int tid = threadIdx.x;
    int x = blockIdx.x * 16 + (tid & 15);
    int y = blockIdx.y * 4  + ((tid >> 4) & 3);
    int z = blockIdx.z * 4  + (tid >> 6);

    int idx = (z * H_ + y) * W_ + x;

    const float* dfp = df + 3 * (size_t)idx;
    float dz = __builtin_nontemporal_load(dfp + 0);
    float dy = __builtin_nontemporal_load(dfp + 1);
    float dx = __builtin_nontemporal_load(dfp + 2);

    float lz = (float)z + dz;
    float ly = (float)y + dy;
    float lx = (float)x + dx;

    // Reference semantics: loc0c = clip(floor(loc), 0, max); loc1 = clip(loc0c+1, 0, max)
    float z0f = fminf(fmaxf(floorf(lz), 0.f), (float)(D_ - 1));
    float y0f = fminf(fmaxf(floorf(ly), 0.f), (float)(H_ - 1));
    float x0f = fminf(fmaxf(floorf(lx), 0.f), (float)(W_ - 1));
    float z1f = fminf(z0f + 1.f, (float)(D_ - 1));
    float y1f = fminf(y0f + 1.f, (float)(H_ - 1));
    float x1f = fminf(x0f + 1.f, (float)(W_ - 1));

    float wz0 = z1f - lz, wz1 = 1.f - wz0;
    float wy0 = y1f - ly, wy1 = 1.f - wy0;
    float wx0 = x1f - lx, wx1 = 1.f - wx0;

    int iz0 = (int)z0f, iz1 = (int)z1f;
    int iy0 = (int)y0f, iy1 = (int)y1f;
    int ix0 = (int)x0f;

    bool edge = ix0 >= W_ - 1;
    int a = edge ? W_ - 2 : ix0;

    int b00 = (iz0 * H_ + iy0) * W_ + a;
    int b01 = (iz0 * H_ + iy1) * W_ + a;
    int b10 = (iz1 * H_ + iy0) * W_ + a;
    int b11 = (iz1 * H_ + iy1) * W_ + a;

    float4 v000, v001, v010, v011, v100, v101, v110, v111;
    load_pair(volh + b00, edge, v000, v001);
    load_pair(volh + b01, edge, v010, v011);
    load_pair(volh + b10, edge, v100, v101);
    load_pair(volh + b11, edge, v110, v111);

    float w000 = wz0 * wy0 * wx0;
    float w001 = wz0 * wy0 * wx1;
    float w010 = wz0 * wy1 * wx0;
    float w011 = wz0 * wy1 * wx1;
    float w100 = wz1 * wy0 * wx0;
    float w101 = wz1 * wy0 * wx1;
    float w110 = wz1 * wy1 * wx0;
    float w111 = wz1 * wy1 * wx1;

    f32x4 r;
    r.x = w000 * v000.x + w001 * v001.x + w010 * v010.x + w011 * v011.x
        + w100 * v100.x + w101 * v101.x + w110 * v110.x + w111 * v111.x;
    r.y = w000 * v000.y + w001 * v001.y + w010 * v010.y + w011 * v011.y
        + w100 * v100.y + w101 * v101.y + w110 * v110.y + w111 * v111.y;
    r.z = w000 * v000.z + w001 * v001.z + w010 * v010.z + w011 * v011.z
        + w100 * v100.z + w101 * v101.z + w110 * v110.z + w111 * v111.z;
    r.w = w000 * v000.w + w001 * v001.w + w010 * v010.w + w011 * v011.w
        + w100 * v100.w + w101 * v101.w + w110 * v110.w + w111 * v111.w;

    __builtin_nontemporal_store(r, (f32x4*)(out + 4 * (size_t)idx));
}

// ---------------------------------------------------------------------------
// Fallback (ws too small): round-2 pure-f32 gather kernel.
// ---------------------------------------------------------------------------
__global__ __launch_bounds__(256) void st_f32_kernel(
    const float4* __restrict__ vol,
    const float*  __restrict__ df,
    float4*       __restrict__ out)
{
    int tid = threadIdx.x;
    int x = blockIdx.x * 16 + (tid & 15);
    int y = blockIdx.y * 4  + ((tid >> 4) & 3);
    int z = blockIdx.z * 4  + (tid >> 6);
    int idx = (z * H_ + y) * W_ + x;

    float dz = df[3 * idx + 0];
    float dy = df[3 * idx + 1];
    float dx = df[3 * idx + 2];
    float lz = (float)z + dz, ly = (float)y + dy, lx = (float)x + dx;

    float z0f = fminf(fmaxf(floorf(lz), 0.f), (float)(D_ - 1));
    float y0f = fminf(fmaxf(floorf(ly), 0.f), (float)(H_ - 1));
    float x0f = fminf(fmaxf(floorf(lx), 0.f), (float)(W_ - 1));
    float z1f = fminf(z0f + 1.f, (float)(D_ - 1));
    float y1f = fminf(y0f + 1.f, (float)(H_ - 1));
    float x1f = fminf(x0f + 1.f, (float)(W_ - 1));

    float wz0 = z1f - lz, wz1 = 1.f - wz0;
    float wy0 = y1f - ly, wy1 = 1.f - wy0;
    float wx0 = x1f - lx, wx1 = 1.f - wx0;

    int iz0 = (int)z0f, iz1 = (int)z1f;
    int iy0 = (int)y0f, iy1 = (int)y1f;
    int ix0 = (int)x0f, ix1 = (int)x1f;

    int b00 = (iz0 * H_ + iy0) * W_;
    int b01 = (iz0 * H_ + iy1) * W_;
    int b10 = (iz1 * H_ + iy0) * W_;
    int b11 = (iz1 * H_ + iy1) * W_;

    float4 v000 = vol[b00 + ix0];
    float4 v001 = vol[b00 + ix1];
    float4 v010 = vol[b01 + ix0];
    float4 v011 = vol[b01 + ix1];
    float4 v100 = vol[b10 + ix0];
    float4 v101 = vol[b10 + ix1];
    float4 v110 = vol[b11 + ix0];
    float4 v111 = vol[b11 + ix1];

    float w000 = wz0*wy0*wx0, w001 = wz0*wy0*wx1;
    float w010 = wz0*wy1*wx0, w011 = wz0*wy1*wx1;
    float w100 = wz1*wy0*wx0, w101 = wz1*wy0*wx1;
    float w110 = wz1*wy1*wx0, w111 = wz1*wy1*wx1;

    float4 r;
    r.x = w000*v000.x + w001*v001.x + w010*v010.x + w011*v011.x
        + w100*v100.x + w101*v101.x + w110*v110.x + w111*v111.x;
    r.y = w000*v000.y + w001*v001.y + w010*v010.y + w011*v011.y
        + w100*v100.y + w101*v101.y + w110*v110.y + w111*v111.y;
    r.z = w000*v000.z + w001*v001.z + w010*v010.z + w011*v011.z
        + w100*v100.z + w101*v101.z + w110*v110.z + w111*v111.z;
    r.w = w000*v000.w + w001*v001.w + w010*v010.w + w011*v011.w
        + w100*v100.w + w101*v101.w + w110*v110.w + w111*v111.w;

    out[idx] = r;
}

extern "C" void kernel_launch(void* const* d_in, const int* in_sizes, int n_in,
                              void* d_out, int out_size, void* d_ws, size_t ws_size,
                              hipStream_t stream) {
    const float4* vol = (const float4*)d_in[0];  // (160,192,160,4) f32
    const float*  df  = (const float*)d_in[1];   // (160,192,160,3) f32
    float4* out = (float4*)d_out;

    dim3 grid(W_ / 16, H_ / 4, D_ / 4);  // 10 x 48 x 40

    size_t need = (size_t)NV * 8;  // half4 per voxel
    if (ws_size >= need) {
        int pairs = NV / 2;
        vol_to_half_kernel<<<(pairs + 255) / 256, 256, 0, stream>>>(
            vol, (uint4*)d_ws);
        st_half_kernel<<<grid, 256, 0, stream>>>(
            (const uint2*)d_ws, df, (float*)out);
    } else {
        st_f32_kernel<<<grid, 256, 0, stream>>>(vol, df, out);
    }
}